// Round 17
// baseline (284.121 us; speedup 1.0000x reference)
//
#include <hip/hip_runtime.h>
#include <cmath>

typedef unsigned short ushort;
typedef __bf16 bf16x8 __attribute__((ext_vector_type(8)));
typedef float f32x4 __attribute__((ext_vector_type(4)));
typedef float f32x16 __attribute__((ext_vector_type(16)));
typedef unsigned int uint4v __attribute__((ext_vector_type(4)));
typedef unsigned int u2v __attribute__((ext_vector_type(2)));
typedef unsigned short ushort4v __attribute__((ext_vector_type(4)));

#define BB 2
#define TT 2048
#define DD 2048
#define HH 16
#define LATD 512
#define RDD 64
#define HDD 128
#define BT 4096
#define LDQ 2048
#define LDK 4096
#define LD1 1088

__device__ __forceinline__ ushort f2bf(float f) {
  union { float f; unsigned u; } v; v.f = f;
  return (ushort)((v.u + 0x7fffu + ((v.u >> 16) & 1u)) >> 16);
}
__device__ __forceinline__ float bf2f(ushort u) {
  union { unsigned u; float f; } v; v.u = ((unsigned)u) << 16; return v.f;
}
__device__ __forceinline__ f32x4 f4zero() {
  f32x4 v; v[0] = 0.f; v[1] = 0.f; v[2] = 0.f; v[3] = 0.f; return v;
}
__device__ __forceinline__ unsigned pkbf(float a, float b) {
  unsigned r;
  asm("v_cvt_pk_bf16_f32 %0, %1, %2" : "=v"(r) : "v"(a), "v"(b));
  return r;  // lo16 = bf16(a), hi16 = bf16(b)
}
__device__ __forceinline__ u2v pl32(unsigned a, unsigned b) {
  return __builtin_amdgcn_permlane32_swap(a, b, false, false);
}
__device__ __forceinline__ float xswap32(float v, int hl) {
  union { float f; unsigned u; } a; a.f = v;
  u2v r = pl32(a.u, a.u);
  union { unsigned u; float f; } o; o.u = hl ? r[0] : r[1];
  return o.f;
}

typedef __attribute__((address_space(1))) void g_void;
typedef __attribute__((address_space(3))) void l_void;
__device__ __forceinline__ void gld16(void* lds, const void* g) {
  __builtin_amdgcn_global_load_lds((g_void*)(unsigned long long)g, (l_void*)lds, 16, 0, 0);
}

// ---------- merged prep: x->bf16 cvt (bid<8192), rope tables (<8448), 8 weight transposes ----------
__global__ void k_prep(const float* __restrict__ x, ushort* __restrict__ xb,
                       float* __restrict__ cosT, float* __restrict__ sinT,
                       const float* __restrict__ Wqd, const float* __restrict__ Wkvd,
                       const float* __restrict__ Wkr, const float* __restrict__ Wqu,
                       const float* __restrict__ Wqr, const float* __restrict__ Wku,
                       const float* __restrict__ Wvu, const float* __restrict__ Wo,
                       ushort* __restrict__ w1T, ushort* __restrict__ w2T,
                       ushort* __restrict__ w3T, ushort* __restrict__ woT) {
  __shared__ float t[32][33];
  int bid = blockIdx.x, tid = threadIdx.x;
  if (bid < 8192) {  // cvt
    int i = bid * 256 + tid;
    f32x4 v = *(const f32x4*)(x + (size_t)i * 4);
    ushort4v u;
#pragma unroll
    for (int r = 0; r < 4; ++r) u[r] = f2bf(v[r]);
    *(ushort4v*)(xb + (size_t)i * 4) = u;
    return;
  }
  if (bid < 8448) {  // rope tables
    int i = (bid - 8192) * 256 + tid;
    int tt = i >> 5, jj = i & 31;
    float freq = exp2f(-(float)jj * (13.287712379549449f / 32.0f));
    float ang = (float)tt * freq;
    float s, c;
    sincosf(ang, &s, &c);
    cosT[i] = c; sinT[i] = s;
    return;
  }
  bid -= 8448;
  const float* in; ushort* out; int R, C, gx;
  if (bid < 1024)      { in = Wqd;  out = w1T;                          R = 2048; C = 512;  gx = 16; }
  else if (bid < 2048) { in = Wkvd; out = w1T + (size_t)512 * 2048;     R = 2048; C = 512;  gx = 16; bid -= 1024; }
  else if (bid < 2176) { in = Wkr;  out = w1T + (size_t)1024 * 2048;    R = 2048; C = 64;   gx = 2;  bid -= 2048; }
  else if (bid < 3200) { in = Wqu;  out = w2T;                          R = 512;  C = 2048; gx = 64; bid -= 2176; }
  else if (bid < 3712) { in = Wqr;  out = w2T + (size_t)2048 * 512;     R = 512;  C = 1024; gx = 32; bid -= 3200; }
  else if (bid < 4736) { in = Wku;  out = w3T;                          R = 512;  C = 2048; gx = 64; bid -= 3712; }
  else if (bid < 5760) { in = Wvu;  out = w3T + (size_t)2048 * 512;     R = 512;  C = 2048; gx = 64; bid -= 4736; }
  else                 { in = Wo;   out = woT;                          R = 2048; C = 2048; gx = 64; bid -= 5760; }
  int c0 = (bid % gx) * 32, r0 = (bid / gx) * 32;
  int tx = tid & 31, ty = tid >> 5;
#pragma unroll
  for (int i = 0; i < 4; ++i)
    t[ty + i * 8][tx] = in[(size_t)(r0 + ty + i * 8) * C + c0 + tx];
  __syncthreads();
#pragma unroll
  for (int i = 0; i < 4; ++i)
    out[(size_t)(c0 + ty + i * 8) * R + r0 + tx] = f2bf(t[tx][ty + i * 8]);
}

// ---------- per-head V transpose: kv slice (stride LDK) -> (b,h,d,t) ----------
__global__ void k_vt(const ushort* __restrict__ in, ushort* __restrict__ out) {
  __shared__ ushort tile[32][33];
  int bh = blockIdx.z, b = bh >> 4, h = bh & 15;
  int t0 = blockIdx.x * 32, d0 = blockIdx.y * 32;
  int tx = threadIdx.x, ty = threadIdx.y;
#pragma unroll
  for (int i = 0; i < 4; ++i)
    tile[ty + i * 8][tx] = in[(size_t)(b * TT + t0 + ty + i * 8) * LDK + h * HDD + d0 + tx];
  __syncthreads();
#pragma unroll
  for (int i = 0; i < 4; ++i)
    out[(size_t)(bh * HDD + d0 + ty + i * 8) * TT + t0 + tx] = tile[tx][ty + i * 8];
}

// ---------- GEMM v2: 2-phase dbuf LDS (stage next || compute cur, 1 barrier/K-step) ----------
template <typename OutT>
__global__ __launch_bounds__(256) void k_gemm(const ushort* __restrict__ A,
                                              const ushort* __restrict__ Bt,
                                              OutT* __restrict__ C,
                                              int M, int N, int K, int lda, int ldc, float alpha) {
  __shared__ __align__(16) ushort As[2][128 * 64];
  __shared__ __align__(16) ushort Bs[2][128 * 64];
  int tid = threadIdx.x;
  int lane = tid & 63, wid = tid >> 6;
  int wm = wid >> 1, wn = wid & 1;
  int lo = lane & 15, hi = lane >> 4;
  int m0 = blockIdx.y * 128, n0 = blockIdx.x * 128;
  int lr = lane >> 3, lc = (lane & 7) * 8;
  f32x4 acc[4][4];
#pragma unroll
  for (int m = 0; m < 4; ++m)
#pragma unroll
    for (int n = 0; n < 4; ++n) acc[m][n] = f4zero();

  auto stage = [&](int buf, int k0) {
#pragma unroll
    for (int it = 0; it < 4; ++it) {
      int c = wid * 4 + it;
      int row = c * 8 + lr;
      gld16(As[buf] + c * 512, A + (size_t)(m0 + row) * lda + k0 + lc);
      gld16(Bs[buf] + c * 512, Bt + (size_t)(n0 + row) * K + k0 + lc);
    }
  };

  stage(0, 0);
  __syncthreads();
  int cur = 0;
  for (int k0 = 0; k0 < K; k0 += 64) {
    if (k0 + 64 < K) stage(cur ^ 1, k0 + 64);
#pragma unroll
    for (int kk = 0; kk < 2; ++kk) {
      bf16x8 af[4], bfr[4];
#pragma unroll
      for (int m = 0; m < 4; ++m)
        af[m] = *(const bf16x8*)(As[cur] + (wm * 64 + m * 16 + lo) * 64 + kk * 32 + hi * 8);
#pragma unroll
      for (int n = 0; n < 4; ++n)
        bfr[n] = *(const bf16x8*)(Bs[cur] + (wn * 64 + n * 16 + lo) * 64 + kk * 32 + hi * 8);
      __builtin_amdgcn_s_setprio(1);
#pragma unroll
      for (int m = 0; m < 4; ++m)
#pragma unroll
        for (int n = 0; n < 4; ++n)
          acc[m][n] = __builtin_amdgcn_mfma_f32_16x16x32_bf16(af[m], bfr[n], acc[m][n], 0, 0, 0);
      __builtin_amdgcn_s_setprio(0);
    }
    __syncthreads();  // drains gld16 (next buf ready) + all reads of cur done
    cur ^= 1;
  }
#pragma unroll
  for (int m = 0; m < 4; ++m)
#pragma unroll
    for (int n = 0; n < 4; ++n)
#pragma unroll
      for (int r = 0; r < 4; ++r) {
        int row = m0 + wm * 64 + m * 16 + hi * 4 + r;
        int col = n0 + wn * 64 + n * 16 + lo;
        if (col < N) {
          float v = acc[m][n][r] * alpha;
          if constexpr (sizeof(OutT) == 4) C[(size_t)row * ldc + col] = v;
          else C[(size_t)row * ldc + col] = f2bf(v);
        }
      }
}

// ---------- G1 v3: 64-row tiles for grid balance (9 x 64 = 576 blocks, 3/CU capacity) ----------
// Wave w owns rows [w*16, w*16+16) x 128 cols. bx==8: kr columns roped in-register.
__global__ __launch_bounds__(256) void k_gemm1(const ushort* __restrict__ A, const ushort* __restrict__ Bt,
                                               ushort* __restrict__ C, ushort* __restrict__ Kr,
                                               const float* __restrict__ cosT, const float* __restrict__ sinT) {
  __shared__ __align__(16) ushort As[2][64 * 64];
  __shared__ __align__(16) ushort Bs[2][128 * 64];
  const int K = DD, lda = DD, ldc = LD1;
  int tid = threadIdx.x;
  int lane = tid & 63, w = tid >> 6;
  int lo = lane & 15, hi = lane >> 4;
  int m0 = blockIdx.y * 64, n0 = blockIdx.x * 128;
  int bx = blockIdx.x;
  f32x4 acc[8];
#pragma unroll
  for (int n = 0; n < 8; ++n) acc[n] = f4zero();

  auto stage = [&](int buf, int k0) {
#pragma unroll
    for (int it = 0; it < 2; ++it) {  // A: 512 x 16B chunks
      int cb = (tid & ~63) + it * 256;
      int c = cb + lane;
      int row = c >> 3, cc = c & 7;
      gld16(As[buf] + cb * 8, A + (size_t)(m0 + row) * lda + k0 + cc * 8);
    }
#pragma unroll
    for (int it = 0; it < 4; ++it) {  // B: 1024 x 16B chunks
      int cb = (tid & ~63) + it * 256;
      int c = cb + lane;
      int row = c >> 3, cc = c & 7;
      gld16(Bs[buf] + cb * 8, Bt + (size_t)(n0 + row) * K + k0 + cc * 8);
    }
  };

  stage(0, 0);
  __syncthreads();
  int cur = 0;
  for (int k0 = 0; k0 < K; k0 += 64) {
    if (k0 + 64 < K) stage(cur ^ 1, k0 + 64);
#pragma unroll
    for (int kk = 0; kk < 2; ++kk) {
      bf16x8 af = *(const bf16x8*)(As[cur] + (w * 16 + lo) * 64 + kk * 32 + hi * 8);
      bf16x8 bfr[8];
#pragma unroll
      for (int n = 0; n < 8; ++n)
        bfr[n] = *(const bf16x8*)(Bs[cur] + (n * 16 + lo) * 64 + kk * 32 + hi * 8);
      __builtin_amdgcn_s_setprio(1);
#pragma unroll
      for (int n = 0; n < 8; ++n)
        acc[n] = __builtin_amdgcn_mfma_f32_16x16x32_bf16(af, bfr[n], acc[n], 0, 0, 0);
      __builtin_amdgcn_s_setprio(0);
    }
    __syncthreads();
    cur ^= 1;
  }
  if (bx < 8) {
#pragma unroll
    for (int n = 0; n < 8; ++n)
#pragma unroll
      for (int r = 0; r < 4; ++r) {
        int row = m0 + w * 16 + hi * 4 + r;
        int col = n0 + n * 16 + lo;
        C[(size_t)row * ldc + col] = f2bf(acc[n][r]);
      }
  } else {  // kr: cols 0..63 valid; rope in-register -> Kr (stride 64)
#pragma unroll
    for (int r = 0; r < 4; ++r) {
      int row = m0 + w * 16 + hi * 4 + r;
      int t = row & (TT - 1);
      float c0 = cosT[t * 32 + lo],      s0 = sinT[t * 32 + lo];
      float c1 = cosT[t * 32 + 16 + lo], s1 = sinT[t * 32 + 16 + lo];
      float x0 = acc[0][r], x1 = acc[1][r];
      float x2 = acc[2][r], x3 = acc[3][r];
      size_t base = (size_t)row * 64 + lo;
      Kr[base +  0] = f2bf(x0 * c0 - x2 * s0);
      Kr[base + 16] = f2bf(x1 * c1 - x3 * s1);
      Kr[base + 32] = f2bf(x2 * c0 + x0 * s0);
      Kr[base + 48] = f2bf(x3 * c1 + x1 * s1);
    }
  }
}

// ---------- merged G2+G3 (2-phase) with fused qr-rope epilogue ----------
// bx<16: q -> stride 2048 *a1; 16..23: qr rope -> stride 1024; >=24: kv -> stride 4096.
__global__ __launch_bounds__(256) void k_gemm23(const ushort* __restrict__ A1, const ushort* __restrict__ B1,
                                                ushort* __restrict__ Cq, ushort* __restrict__ Cr,
                                                const ushort* __restrict__ A2, const ushort* __restrict__ B2,
                                                ushort* __restrict__ Ckv, float a1,
                                                const float* __restrict__ cosT, const float* __restrict__ sinT) {
  __shared__ __align__(16) ushort As[2][128 * 64];
  __shared__ __align__(16) ushort Bs[2][128 * 64];
  int bx = blockIdx.x;
  const ushort* A; const ushort* Bt; int n0;
  if (bx < 24) { A = A1; Bt = B1; n0 = bx * 128; }
  else         { A = A2; Bt = B2; n0 = (bx - 24) * 128; }
  const int K = LATD, lda = LD1;
  int tid = threadIdx.x;
  int lane = tid & 63, wid = tid >> 6;
  int wm = wid >> 1, wn = wid & 1;
  int lo = lane & 15, hi = lane >> 4;
  int m0 = blockIdx.y * 128;
  int lr = lane >> 3, lc = (lane & 7) * 8;
  f32x4 acc[4][4];
#pragma unroll
  for (int m = 0; m < 4; ++m)
#pragma unroll
    for (int n = 0; n < 4; ++n) acc[m][n] = f4zero();

  auto stage = [&](int buf, int k0) {
#pragma unroll
    for (int it = 0; it < 4; ++it) {
      int c = wid * 4 + it;
      int row = c * 8 + lr;
      gld16(As[buf] + c * 512, A + (size_t)(m0 + row) * lda + k0 + lc);
      gld16(Bs[buf] + c * 512, Bt + (size_t)(n0 + row) * K + k0 + lc);
    }
  };

  stage(0, 0);
  __syncthreads();
  int cur = 0;
  for (int k0 = 0; k0 < K; k0 += 64) {
    if (k0 + 64 < K) stage(cur ^ 1, k0 + 64);
#pragma unroll
    for (int kk = 0; kk < 2; ++kk) {
      bf16x8 af[4], bfr[4];
#pragma unroll
      for (int m = 0; m < 4; ++m)
        af[m] = *(const bf16x8*)(As[cur] + (wm * 64 + m * 16 + lo) * 64 + kk * 32 + hi * 8);
#pragma unroll
      for (int n = 0; n < 4; ++n)
        bfr[n] = *(const bf16x8*)(Bs[cur] + (wn * 64 + n * 16 + lo) * 64 + kk * 32 + hi * 8);
      __builtin_amdgcn_s_setprio(1);
#pragma unroll
      for (int m = 0; m < 4; ++m)
#pragma unroll
        for (int n = 0; n < 4; ++n)
          acc[m][n] = __builtin_amdgcn_mfma_f32_16x16x32_bf16(af[m], bfr[n], acc[m][n], 0, 0, 0);
      __builtin_amdgcn_s_setprio(0);
    }
    __syncthreads();
    cur ^= 1;
  }
  if (bx < 16) {
#pragma unroll
    for (int m = 0; m < 4; ++m)
#pragma unroll
      for (int n = 0; n < 4; ++n)
#pragma unroll
        for (int r = 0; r < 4; ++r) {
          int row = m0 + wm * 64 + m * 16 + hi * 4 + r;
          int col = n0 + wn * 64 + n * 16 + lo;
          Cq[(size_t)row * 2048 + col] = f2bf(acc[m][n][r] * a1);
        }
  } else if (bx < 24) {
#pragma unroll
    for (int m = 0; m < 4; ++m)
#pragma unroll
      for (int r = 0; r < 4; ++r) {
        int row = m0 + wm * 64 + m * 16 + hi * 4 + r;
        int t = row & (TT - 1);
        float c0 = cosT[t * 32 + lo],      s0 = sinT[t * 32 + lo];
        float c1 = cosT[t * 32 + 16 + lo], s1 = sinT[t * 32 + 16 + lo];
        float x0 = acc[m][0][r], x1 = acc[m][1][r];
        float x2 = acc[m][2][r], x3 = acc[m][3][r];
        size_t base = (size_t)row * 1024 + (bx - 16) * 128 + wn * 64 + lo;
        Cr[base +  0] = f2bf((x0 * c0 - x2 * s0) * a1);
        Cr[base + 16] = f2bf((x1 * c1 - x3 * s1) * a1);
        Cr[base + 32] = f2bf((x2 * c0 + x0 * s0) * a1);
        Cr[base + 48] = f2bf((x3 * c1 + x1 * s1) * a1);
      }
  } else {
#pragma unroll
    for (int m = 0; m < 4; ++m)
#pragma unroll
      for (int n = 0; n < 4; ++n)
#pragma unroll
        for (int r = 0; r < 4; ++r) {
          int row = m0 + wm * 64 + m * 16 + hi * 4 + r;
          int col = n0 + wn * 64 + n * 16 + lo;
          Ckv[(size_t)row * 4096 + col] = f2bf(acc[m][n][r]);
        }
  }
}

// ---------- causal flash attention (round-13 proven config) ----------
__global__ __launch_bounds__(256, 2) void k_attn(const ushort* __restrict__ qb, const ushort* __restrict__ qrb,
                                                 const ushort* __restrict__ kb, const ushort* __restrict__ krb,
                                                 const ushort* __restrict__ vt, ushort* __restrict__ ao) {
  __shared__ __align__(16) ushort SH[24576];  // [Ks0|Ks1|Kr0|Kr1] = 49152 B
#define KS(buf) (SH + (buf) * 8192)
#define KR(buf) (SH + 16384 + (buf) * 4096)
  const int tid = threadIdx.x, lane = tid & 63, w = tid >> 6;
  const int cq = lane & 31;
  const int hl = lane >> 5;
  const int lin = (int)blockIdx.x + 16 * (int)blockIdx.y + 256 * (int)blockIdx.z;
  const int combo = lin & 31;
  const int pr = lin >> 5, h = combo & 15, b = combo >> 4;
  const int tA = pr, tB = 31 - pr;
  const int nch = tB + 1;
  const int myTile = (w >= 2) ? tB : tA;
  const int myDiag = myTile;
  const int qrow = myTile * 64 + (w & 1) * 32 + cq;
  const int swzK = (cq & 15) << 3;
  const int swzR = (cq & 7) << 3;

  bf16x8 qf[12];
  {
    const ushort* qp = qb + (size_t)(b * TT + qrow) * LDQ + h * HDD;
#pragma unroll
    for (int f = 0; f < 8; ++f) qf[f] = *(const bf16x8*)(qp + f * 16 + hl * 8);
    const ushort* qrp = qrb + (size_t)(b * TT + qrow) * 1024 + h * RDD;
#pragma unroll
    for (int f = 0; f < 4; ++f) qf[8 + f] = *(const bf16x8*)(qrp + f * 16 + hl * 8);
  }
  f32x16 o0, o1, o2, o3;
#pragma unroll
  for (int r = 0; r < 16; ++r) { o0[r] = 0.f; o1[r] = 0.f; o2[r] = 0.f; o3[r] = 0.f; }
  float m = -__builtin_inff(), l = 0.f;

  auto stage = [&](int buf, int kb0) {
#pragma unroll
    for (int it = 0; it < 4; ++it) {
      int cb = (tid & ~63) + it * 256;
      int c = cb + lane;
      int row = c >> 4;
      int ccg = (c & 15) ^ (row & 15);
      gld16(&KS(buf)[cb * 8], kb + (size_t)(b * TT + kb0 + row) * LDK + h * HDD + ccg * 8);
    }
#pragma unroll
    for (int it = 0; it < 2; ++it) {
      int cb = (tid & ~63) + it * 256;
      int c = cb + lane;
      int row = c >> 3;
      int ccg = (c & 7) ^ (row & 7);
      gld16(&KR(buf)[cb * 8], krb + (size_t)(b * TT + kb0 + row) * RDD + ccg * 8);
    }
  };

  stage(0, 0);
  __syncthreads();

  const ushort* vth = vt + (size_t)(b * HH + h) * HDD * TT;

  int cur = 0;
  for (int ch = 0; ch < nch; ++ch) {
    const int kb0 = ch * 64;
    if (ch + 1 < nch) stage(cur ^ 1, kb0 + 64);

    if (ch <= myDiag) {  // wave-uniform skip of dead chunks
      f32x16 s0, s1;
#pragma unroll
      for (int r = 0; r < 16; ++r) { s0[r] = 0.f; s1[r] = 0.f; }
      __builtin_amdgcn_s_setprio(1);
#pragma unroll
      for (int f = 0; f < 12; ++f) {
        const ushort* base = (f < 8) ? KS(cur) : KR(cur);
        const int stride = (f < 8) ? 128 : 64;
        const int colU = ((f < 8) ? f * 16 : (f - 8) * 16) + hl * 8;
        const int sz = (f < 8) ? swzK : swzR;
        bf16x8 k0 = *(const bf16x8*)(base + cq * stride + (colU ^ sz));
        bf16x8 k1 = *(const bf16x8*)(base + (32 + cq) * stride + (colU ^ sz));
        s0 = __builtin_amdgcn_mfma_f32_32x32x16_bf16(k0, qf[f], s0, 0, 0, 0);
        s1 = __builtin_amdgcn_mfma_f32_32x32x16_bf16(k1, qf[f], s1, 0, 0, 0);
      }
      __builtin_amdgcn_s_setprio(0);

      float mx = -__builtin_inff();
      if (ch == myDiag) {
#pragma unroll
        for (int r = 0; r < 16; ++r) {
          int kp = kb0 + (r & 3) + 8 * (r >> 2) + 4 * hl;
          if (kp > qrow) s0[r] = -__builtin_inff();
          mx = fmaxf(mx, s0[r]);
          if (kp + 32 > qrow) s1[r] = -__builtin_inff();
          mx = fmaxf(mx, s1[r]);
        }
      } else {
#pragma unroll
        for (int r = 0; r < 16; ++r) mx = fmaxf(fmaxf(mx, s0[r]), s1[r]);
      }
      mx = fmaxf(mx, xswap32(mx, hl));

      uint4v va[4], vb2[4];
      {
        const ushort* vp = vth + (size_t)(0 * 32 + cq) * TT + kb0 + hl * 8;
        va[0] = *(const uint4v*)(vp);
        va[1] = *(const uint4v*)(vp + 16);
        va[2] = *(const uint4v*)(vp + 32);
        va[3] = *(const uint4v*)(vp + 48);
      }

      bool defer = __all(mx <= m + 8.f);  // T13
      float mnew = defer ? m : fmaxf(m, mx);
      float rs = 0.f;
#pragma unroll
      for (int r = 0; r < 16; ++r) {
        s0[r] = exp2f(s0[r] - mnew); rs += s0[r];
        s1[r] = exp2f(s1[r] - mnew); rs += s1[r];
      }
      rs += xswap32(rs, hl);
      if (!defer) {
        float al = exp2f(m - mnew);
#pragma unroll
        for (int r = 0; r < 16; ++r) { o0[r] *= al; o1[r] *= al; o2[r] *= al; o3[r] *= al; }
        l = l * al + rs;
        m = mnew;
      } else {
        l += rs;
      }

      bf16x8 pf0, pf1, pf2, pf3;
#define PBUILD(PF, S, RB)                                                   \
      {                                                                     \
        unsigned a2 = pkbf(S[RB + 0], S[RB + 1]);                           \
        unsigned b2 = pkbf(S[RB + 2], S[RB + 3]);                           \
        unsigned c2 = pkbf(S[RB + 4], S[RB + 5]);                           \
        unsigned d2 = pkbf(S[RB + 6], S[RB + 7]);                           \
        u2v r02 = pl32(a2, c2);                                             \
        u2v r13 = pl32(b2, d2);                                             \
        union { uint4v u; bf16x8 v; } pb_;                                  \
        pb_.u[0] = r02[0];                                                  \
        pb_.u[1] = r13[0];                                                  \
        pb_.u[2] = r02[1];                                                  \
        pb_.u[3] = r13[1];                                                  \
        PF = pb_.v;                                                         \
      }
      PBUILD(pf0, s0, 0)
      PBUILD(pf1, s0, 8)
      PBUILD(pf2, s1, 0)
      PBUILD(pf3, s1, 8)
#undef PBUILD

#define VLOAD(DST, DT)                                                      \
      {                                                                     \
        const ushort* vp = vth + (size_t)((DT) * 32 + cq) * TT + kb0 + hl * 8;\
        DST[0] = *(const uint4v*)(vp);                                      \
        DST[1] = *(const uint4v*)(vp + 16);                                 \
        DST[2] = *(const uint4v*)(vp + 32);                                 \
        DST[3] = *(const uint4v*)(vp + 48);                                 \
      }
#define PVSTEP(OD, VS)                                                      \
      {                                                                     \
        union { uint4v u; bf16x8 v; } cv_;                                  \
        __builtin_amdgcn_s_setprio(1);                                      \
        cv_.u = VS[0]; OD = __builtin_amdgcn_mfma_f32_32x32x16_bf16(cv_.v, pf0, OD, 0, 0, 0); \
        cv_.u = VS[1]; OD = __builtin_amdgcn_mfma_f32_32x32x16_bf16(cv_.v, pf1, OD, 0, 0, 0); \
        cv_.u = VS[2]; OD = __builtin_amdgcn_mfma_f32_32x32x16_bf16(cv_.v, pf2, OD, 0, 0, 0); \
        cv_.u = VS[3]; OD = __builtin_amdgcn_mfma_f32_32x32x16_bf16(cv_.v, pf3, OD, 0, 0, 0); \
        __builtin_amdgcn_s_setprio(0);                                      \
      }
      VLOAD(vb2, 1)
      PVSTEP(o0, va)
      VLOAD(va, 2)
      PVSTEP(o1, vb2)
      VLOAD(vb2, 3)
      PVSTEP(o2, va)
      PVSTEP(o3, vb2)
#undef VLOAD
#undef PVSTEP
    }

    __syncthreads();  // drains staged gld16 for buffer cur^1
    cur ^= 1;
  }

  // ---- epilogue: per-wave LDS transpose, coalesced ao writes ----
  float inv = 1.0f / l;
  const int ebase = w * 4352;
#define OSPILL(OD, DT)                                                      \
  _Pragma("unroll")                                                         \
  for (int g = 0; g < 4; ++g) {                                             \
    ushort4v u;                                                             \
    _Pragma("unroll")                                                       \
    for (int j = 0; j < 4; ++j) u[j] = f2bf(OD[g * 4 + j] * inv);           \
    *(ushort4v*)(&SH[ebase + cq * 136 + (DT) * 32 + g * 8 + hl * 4]) = u;   \
  }
  OSPILL(o0, 0)
  OSPILL(o1, 1)
  OSPILL(o2, 2)
  OSPILL(o3, 3)
#undef OSPILL
  {
    const size_t rbase = (size_t)(b * TT + myTile * 64 + (w & 1) * 32);
#pragma unroll
    for (int p = 0; p < 8; ++p) {
      int q = p * 4 + (lane >> 4);
      uint4v v = *(const uint4v*)(&SH[ebase + q * 136 + (lane & 15) * 8]);
      *(uint4v*)(&ao[(rbase + q) * DD + h * HDD + (lane & 15) * 8]) = v;
    }
  }
#undef KS
#undef KR
}

extern "C" void kernel_launch(void* const* d_in, const int* in_sizes, int n_in,
                              void* d_out, int out_size, void* d_ws, size_t ws_size,
                              hipStream_t stream) {
  (void)in_sizes; (void)n_in; (void)out_size; (void)ws_size;
  const float* x    = (const float*)d_in[0];
  const float* Wqd  = (const float*)d_in[1];
  const float* Wqu  = (const float*)d_in[2];
  const float* Wqr  = (const float*)d_in[3];
  const float* Wkvd = (const float*)d_in[4];
  const float* Wku  = (const float*)d_in[5];
  const float* Wvu  = (const float*)d_in[6];
  const float* Wkr  = (const float*)d_in[7];
  const float* Wo   = (const float*)d_in[8];
  float* out = (float*)d_out;

  char* ws = (char*)d_ws;
  size_t off = 0;
  auto alloc = [&](size_t bytes) { void* p = ws + off; off += (bytes + 255) & ~(size_t)255; return p; };
  ushort* xb   = (ushort*)alloc((size_t)BT * DD * 2);
  ushort* w1T  = (ushort*)alloc((size_t)(LD1 + 64) * DD * 2);
  ushort* w2T  = (ushort*)alloc((size_t)3072 * LATD * 2);
  ushort* w3T  = (ushort*)alloc((size_t)4096 * LATD * 2);
  ushort* woT  = (ushort*)alloc((size_t)DD * DD * 2);
  ushort* xc   = (ushort*)alloc((size_t)BT * LD1 * 2);
  ushort* qqr  = (ushort*)alloc((size_t)BT * 2048 * 2);
  ushort* kv   = (ushort*)alloc((size_t)BT * 4096 * 2);   // [k | v], stride 4096
  ushort* qrB  = (ushort*)alloc((size_t)BT * 1024 * 2);
  ushort* krB  = (ushort*)alloc((size_t)BT * RDD * 2);
  ushort* vtB  = (ushort*)alloc((size_t)BT * DD * 2);
  ushort* aoB  = (ushort*)alloc((size_t)BT * DD * 2);
  float*  cosT = (float*)alloc((size_t)TT * 32 * 4);
  float*  sinT = (float*)alloc((size_t)TT * 32 * 4);

  float qscale = 1.4426950408889634f / sqrtf(192.0f);

  // prep: cvt (8192 blocks) + tables (256) + 8 weight transposes (9856)
  k_prep<<<dim3(18304), 256, 0, stream>>>(x, xb, cosT, sinT,
                                          Wqd, Wkvd, Wkr, Wqu, Wqr, Wku, Wvu, Wo,
                                          w1T, w2T, w3T, woT);

  // G1 (+ fused kr rope): xc = x @ [Wqd|Wkvd|Wkr], krB = rope(kr); 64-row tiles
  k_gemm1<<<dim3(9, BT / 64), 256, 0, stream>>>(xb, w1T, xc, krB, cosT, sinT);
  // G2+G3 merged (fused qr-rope): q->qqr, rope(qr)->qrB, kv->kv
  k_gemm23<<<dim3(56, BT / 128), 256, 0, stream>>>(xc, w2T, qqr, qrB, xc + 512, w3T, kv,
                                                   qscale, cosT, sinT);

  k_vt<<<dim3(TT / 32, HDD / 32, BB * HH), dim3(32, 8), 0, stream>>>(kv + 2048, vtB);

  k_attn<<<dim3(16, HH, BB), 256, 0, stream>>>(qqr, qrB, kv, krB, vtB, aoB);

  // G4: out = ao @ Wo
  k_gemm<float><<<dim3(16, BT / 128), 256, 0, stream>>>(aoB, woT, out, BT, DD, DD, DD, DD, 1.0f);
}

// Round 18
// 270.647 us; speedup vs baseline: 1.0498x; 1.0498x over previous
//
#include <hip/hip_runtime.h>
#include <cmath>

typedef unsigned short ushort;
typedef __bf16 bf16x8 __attribute__((ext_vector_type(8)));
typedef float f32x4 __attribute__((ext_vector_type(4)));
typedef float f32x16 __attribute__((ext_vector_type(16)));
typedef unsigned int uint4v __attribute__((ext_vector_type(4)));
typedef unsigned int u2v __attribute__((ext_vector_type(2)));
typedef unsigned short ushort4v __attribute__((ext_vector_type(4)));

#define BB 2
#define TT 2048
#define DD 2048
#define HH 16
#define LATD 512
#define RDD 64
#define HDD 128
#define BT 4096
#define LDQ 2048
#define LDK 4096
#define LD1 1088

__device__ __forceinline__ ushort f2bf(float f) {
  union { float f; unsigned u; } v; v.f = f;
  return (ushort)((v.u + 0x7fffu + ((v.u >> 16) & 1u)) >> 16);
}
__device__ __forceinline__ float bf2f(ushort u) {
  union { unsigned u; float f; } v; v.u = ((unsigned)u) << 16; return v.f;
}
__device__ __forceinline__ f32x4 f4zero() {
  f32x4 v; v[0] = 0.f; v[1] = 0.f; v[2] = 0.f; v[3] = 0.f; return v;
}
__device__ __forceinline__ unsigned pkbf(float a, float b) {
  unsigned r;
  asm("v_cvt_pk_bf16_f32 %0, %1, %2" : "=v"(r) : "v"(a), "v"(b));
  return r;  // lo16 = bf16(a), hi16 = bf16(b)
}
__device__ __forceinline__ u2v pl32(unsigned a, unsigned b) {
  return __builtin_amdgcn_permlane32_swap(a, b, false, false);
}
__device__ __forceinline__ float xswap32(float v, int hl) {
  union { float f; unsigned u; } a; a.f = v;
  u2v r = pl32(a.u, a.u);
  union { unsigned u; float f; } o; o.u = hl ? r[0] : r[1];
  return o.f;
}

typedef __attribute__((address_space(1))) void g_void;
typedef __attribute__((address_space(3))) void l_void;
__device__ __forceinline__ void gld16(void* lds, const void* g) {
  __builtin_amdgcn_global_load_lds((g_void*)(unsigned long long)g, (l_void*)lds, 16, 0, 0);
}

// ---------- merged prep: x->bf16 cvt (bid<8192), rope tables (<8448), 8 weight transposes ----------
__global__ void k_prep(const float* __restrict__ x, ushort* __restrict__ xb,
                       float* __restrict__ cosT, float* __restrict__ sinT,
                       const float* __restrict__ Wqd, const float* __restrict__ Wkvd,
                       const float* __restrict__ Wkr, const float* __restrict__ Wqu,
                       const float* __restrict__ Wqr, const float* __restrict__ Wku,
                       const float* __restrict__ Wvu, const float* __restrict__ Wo,
                       ushort* __restrict__ w1T, ushort* __restrict__ w2T,
                       ushort* __restrict__ w3T, ushort* __restrict__ woT) {
  __shared__ float t[32][33];
  int bid = blockIdx.x, tid = threadIdx.x;
  if (bid < 8192) {  // cvt
    int i = bid * 256 + tid;
    f32x4 v = *(const f32x4*)(x + (size_t)i * 4);
    ushort4v u;
#pragma unroll
    for (int r = 0; r < 4; ++r) u[r] = f2bf(v[r]);
    *(ushort4v*)(xb + (size_t)i * 4) = u;
    return;
  }
  if (bid < 8448) {  // rope tables
    int i = (bid - 8192) * 256 + tid;
    int tt = i >> 5, jj = i & 31;
    float freq = exp2f(-(float)jj * (13.287712379549449f / 32.0f));
    float ang = (float)tt * freq;
    float s, c;
    sincosf(ang, &s, &c);
    cosT[i] = c; sinT[i] = s;
    return;
  }
  bid -= 8448;
  const float* in; ushort* out; int R, C, gx;
  if (bid < 1024)      { in = Wqd;  out = w1T;                          R = 2048; C = 512;  gx = 16; }
  else if (bid < 2048) { in = Wkvd; out = w1T + (size_t)512 * 2048;     R = 2048; C = 512;  gx = 16; bid -= 1024; }
  else if (bid < 2176) { in = Wkr;  out = w1T + (size_t)1024 * 2048;    R = 2048; C = 64;   gx = 2;  bid -= 2048; }
  else if (bid < 3200) { in = Wqu;  out = w2T;                          R = 512;  C = 2048; gx = 64; bid -= 2176; }
  else if (bid < 3712) { in = Wqr;  out = w2T + (size_t)2048 * 512;     R = 512;  C = 1024; gx = 32; bid -= 3200; }
  else if (bid < 4736) { in = Wku;  out = w3T;                          R = 512;  C = 2048; gx = 64; bid -= 3712; }
  else if (bid < 5760) { in = Wvu;  out = w3T + (size_t)2048 * 512;     R = 512;  C = 2048; gx = 64; bid -= 4736; }
  else                 { in = Wo;   out = woT;                          R = 2048; C = 2048; gx = 64; bid -= 5760; }
  int c0 = (bid % gx) * 32, r0 = (bid / gx) * 32;
  int tx = tid & 31, ty = tid >> 5;
#pragma unroll
  for (int i = 0; i < 4; ++i)
    t[ty + i * 8][tx] = in[(size_t)(r0 + ty + i * 8) * C + c0 + tx];
  __syncthreads();
#pragma unroll
  for (int i = 0; i < 4; ++i)
    out[(size_t)(c0 + ty + i * 8) * R + r0 + tx] = f2bf(t[tx][ty + i * 8]);
}

// ---------- per-head V transpose v2: 64x64 tiles, 16B global I/O, XOR-swizzled LDS ----------
__global__ void k_vt(const ushort* __restrict__ in, ushort* __restrict__ out) {
  __shared__ ushort tile[64 * 72];
  int bh = blockIdx.z, b = bh >> 4, h = bh & 15;
  int t0 = blockIdx.x * 64, d0 = blockIdx.y * 64;
  int tid = threadIdx.x;
  int lr = tid >> 3, lc = (tid & 7) * 8;
#pragma unroll
  for (int it = 0; it < 2; ++it) {
    int row = it * 32 + lr;  // t within tile
    uint4v v = *(const uint4v*)(&in[(size_t)(b * TT + t0 + row) * LDK + h * HDD + d0 + lc]);
    *(uint4v*)(&tile[row * 72 + (lc ^ ((row >> 3) << 3))]) = v;
  }
  __syncthreads();
#pragma unroll
  for (int it = 0; it < 2; ++it) {
    int dr = it * 32 + lr;   // d within tile
    union { ushort s[8]; uint4v v; } pk;
#pragma unroll
    for (int j = 0; j < 8; ++j) {
      int row = lc + j;
      pk.s[j] = tile[row * 72 + (((dr & ~7) ^ ((row >> 3) << 3)) | (dr & 7))];
    }
    *(uint4v*)(&out[((size_t)(bh * HDD + d0 + dr)) * TT + t0 + lc]) = pk.v;
  }
}

// ---------- GEMM v2: 2-phase dbuf LDS (stage next || compute cur, 1 barrier/K-step) ----------
template <typename OutT>
__global__ __launch_bounds__(256) void k_gemm(const ushort* __restrict__ A,
                                              const ushort* __restrict__ Bt,
                                              OutT* __restrict__ C,
                                              int M, int N, int K, int lda, int ldc, float alpha) {
  __shared__ __align__(16) ushort As[2][128 * 64];
  __shared__ __align__(16) ushort Bs[2][128 * 64];
  int tid = threadIdx.x;
  int lane = tid & 63, wid = tid >> 6;
  int wm = wid >> 1, wn = wid & 1;
  int lo = lane & 15, hi = lane >> 4;
  int m0 = blockIdx.y * 128, n0 = blockIdx.x * 128;
  int lr = lane >> 3, lc = (lane & 7) * 8;
  f32x4 acc[4][4];
#pragma unroll
  for (int m = 0; m < 4; ++m)
#pragma unroll
    for (int n = 0; n < 4; ++n) acc[m][n] = f4zero();

  auto stage = [&](int buf, int k0) {
#pragma unroll
    for (int it = 0; it < 4; ++it) {
      int c = wid * 4 + it;
      int row = c * 8 + lr;
      gld16(As[buf] + c * 512, A + (size_t)(m0 + row) * lda + k0 + lc);
      gld16(Bs[buf] + c * 512, Bt + (size_t)(n0 + row) * K + k0 + lc);
    }
  };

  stage(0, 0);
  __syncthreads();
  int cur = 0;
  for (int k0 = 0; k0 < K; k0 += 64) {
    if (k0 + 64 < K) stage(cur ^ 1, k0 + 64);
#pragma unroll
    for (int kk = 0; kk < 2; ++kk) {
      bf16x8 af[4], bfr[4];
#pragma unroll
      for (int m = 0; m < 4; ++m)
        af[m] = *(const bf16x8*)(As[cur] + (wm * 64 + m * 16 + lo) * 64 + kk * 32 + hi * 8);
#pragma unroll
      for (int n = 0; n < 4; ++n)
        bfr[n] = *(const bf16x8*)(Bs[cur] + (wn * 64 + n * 16 + lo) * 64 + kk * 32 + hi * 8);
      __builtin_amdgcn_s_setprio(1);
#pragma unroll
      for (int m = 0; m < 4; ++m)
#pragma unroll
        for (int n = 0; n < 4; ++n)
          acc[m][n] = __builtin_amdgcn_mfma_f32_16x16x32_bf16(af[m], bfr[n], acc[m][n], 0, 0, 0);
      __builtin_amdgcn_s_setprio(0);
    }
    __syncthreads();  // drains gld16 (next buf ready) + all reads of cur done
    cur ^= 1;
  }
#pragma unroll
  for (int m = 0; m < 4; ++m)
#pragma unroll
    for (int n = 0; n < 4; ++n)
#pragma unroll
      for (int r = 0; r < 4; ++r) {
        int row = m0 + wm * 64 + m * 16 + hi * 4 + r;
        int col = n0 + wn * 64 + n * 16 + lo;
        if (col < N) {
          float v = acc[m][n][r] * alpha;
          if constexpr (sizeof(OutT) == 4) C[(size_t)row * ldc + col] = v;
          else C[(size_t)row * ldc + col] = f2bf(v);
        }
      }
}

// ---------- G1 (2-phase) with fused kr-rope epilogue (bx==8) ----------
__global__ __launch_bounds__(256) void k_gemm1(const ushort* __restrict__ A, const ushort* __restrict__ Bt,
                                               ushort* __restrict__ C, ushort* __restrict__ Kr,
                                               const float* __restrict__ cosT, const float* __restrict__ sinT) {
  __shared__ __align__(16) ushort As[2][128 * 64];
  __shared__ __align__(16) ushort Bs[2][128 * 64];
  const int K = DD, lda = DD, ldc = LD1;
  int tid = threadIdx.x;
  int lane = tid & 63, wid = tid >> 6;
  int wm = wid >> 1, wn = wid & 1;
  int lo = lane & 15, hi = lane >> 4;
  int m0 = blockIdx.y * 128, n0 = blockIdx.x * 128;
  int bx = blockIdx.x;
  int lr = lane >> 3, lc = (lane & 7) * 8;
  f32x4 acc[4][4];
#pragma unroll
  for (int m = 0; m < 4; ++m)
#pragma unroll
    for (int n = 0; n < 4; ++n) acc[m][n] = f4zero();

  auto stage = [&](int buf, int k0) {
#pragma unroll
    for (int it = 0; it < 4; ++it) {
      int c = wid * 4 + it;
      int row = c * 8 + lr;
      gld16(As[buf] + c * 512, A + (size_t)(m0 + row) * lda + k0 + lc);
      gld16(Bs[buf] + c * 512, Bt + (size_t)(n0 + row) * K + k0 + lc);
    }
  };

  stage(0, 0);
  __syncthreads();
  int cur = 0;
  for (int k0 = 0; k0 < K; k0 += 64) {
    if (k0 + 64 < K) stage(cur ^ 1, k0 + 64);
#pragma unroll
    for (int kk = 0; kk < 2; ++kk) {
      bf16x8 af[4], bfr[4];
#pragma unroll
      for (int m = 0; m < 4; ++m)
        af[m] = *(const bf16x8*)(As[cur] + (wm * 64 + m * 16 + lo) * 64 + kk * 32 + hi * 8);
#pragma unroll
      for (int n = 0; n < 4; ++n)
        bfr[n] = *(const bf16x8*)(Bs[cur] + (wn * 64 + n * 16 + lo) * 64 + kk * 32 + hi * 8);
      __builtin_amdgcn_s_setprio(1);
#pragma unroll
      for (int m = 0; m < 4; ++m)
#pragma unroll
        for (int n = 0; n < 4; ++n)
          acc[m][n] = __builtin_amdgcn_mfma_f32_16x16x32_bf16(af[m], bfr[n], acc[m][n], 0, 0, 0);
      __builtin_amdgcn_s_setprio(0);
    }
    __syncthreads();
    cur ^= 1;
  }
  if (bx < 8) {
#pragma unroll
    for (int m = 0; m < 4; ++m)
#pragma unroll
      for (int n = 0; n < 4; ++n)
#pragma unroll
        for (int r = 0; r < 4; ++r) {
          int row = m0 + wm * 64 + m * 16 + hi * 4 + r;
          int col = n0 + wn * 64 + n * 16 + lo;
          C[(size_t)row * ldc + col] = f2bf(acc[m][n][r]);
        }
  } else if (wn == 0) {
#pragma unroll
    for (int m = 0; m < 4; ++m)
#pragma unroll
      for (int r = 0; r < 4; ++r) {
        int row = m0 + wm * 64 + m * 16 + hi * 4 + r;
        int t = row & (TT - 1);
        float c0 = cosT[t * 32 + lo],      s0 = sinT[t * 32 + lo];
        float c1 = cosT[t * 32 + 16 + lo], s1 = sinT[t * 32 + 16 + lo];
        float x0 = acc[m][0][r], x1 = acc[m][1][r];
        float x2 = acc[m][2][r], x3 = acc[m][3][r];
        size_t base = (size_t)row * 64 + lo;
        Kr[base +  0] = f2bf(x0 * c0 - x2 * s0);
        Kr[base + 16] = f2bf(x1 * c1 - x3 * s1);
        Kr[base + 32] = f2bf(x2 * c0 + x0 * s0);
        Kr[base + 48] = f2bf(x3 * c1 + x1 * s1);
      }
  }
}

// ---------- merged G2+G3 (2-phase) with fused qr-rope epilogue ----------
// bx<16: q -> stride 2048 *a1; 16..23: qr rope -> stride 1024; >=24: kv -> stride 4096.
__global__ __launch_bounds__(256) void k_gemm23(const ushort* __restrict__ A1, const ushort* __restrict__ B1,
                                                ushort* __restrict__ Cq, ushort* __restrict__ Cr,
                                                const ushort* __restrict__ A2, const ushort* __restrict__ B2,
                                                ushort* __restrict__ Ckv, float a1,
                                                const float* __restrict__ cosT, const float* __restrict__ sinT) {
  __shared__ __align__(16) ushort As[2][128 * 64];
  __shared__ __align__(16) ushort Bs[2][128 * 64];
  int bx = blockIdx.x;
  const ushort* A; const ushort* Bt; int n0;
  if (bx < 24) { A = A1; Bt = B1; n0 = bx * 128; }
  else         { A = A2; Bt = B2; n0 = (bx - 24) * 128; }
  const int K = LATD, lda = LD1;
  int tid = threadIdx.x;
  int lane = tid & 63, wid = tid >> 6;
  int wm = wid >> 1, wn = wid & 1;
  int lo = lane & 15, hi = lane >> 4;
  int m0 = blockIdx.y * 128;
  int lr = lane >> 3, lc = (lane & 7) * 8;
  f32x4 acc[4][4];
#pragma unroll
  for (int m = 0; m < 4; ++m)
#pragma unroll
    for (int n = 0; n < 4; ++n) acc[m][n] = f4zero();

  auto stage = [&](int buf, int k0) {
#pragma unroll
    for (int it = 0; it < 4; ++it) {
      int c = wid * 4 + it;
      int row = c * 8 + lr;
      gld16(As[buf] + c * 512, A + (size_t)(m0 + row) * lda + k0 + lc);
      gld16(Bs[buf] + c * 512, Bt + (size_t)(n0 + row) * K + k0 + lc);
    }
  };

  stage(0, 0);
  __syncthreads();
  int cur = 0;
  for (int k0 = 0; k0 < K; k0 += 64) {
    if (k0 + 64 < K) stage(cur ^ 1, k0 + 64);
#pragma unroll
    for (int kk = 0; kk < 2; ++kk) {
      bf16x8 af[4], bfr[4];
#pragma unroll
      for (int m = 0; m < 4; ++m)
        af[m] = *(const bf16x8*)(As[cur] + (wm * 64 + m * 16 + lo) * 64 + kk * 32 + hi * 8);
#pragma unroll
      for (int n = 0; n < 4; ++n)
        bfr[n] = *(const bf16x8*)(Bs[cur] + (wn * 64 + n * 16 + lo) * 64 + kk * 32 + hi * 8);
      __builtin_amdgcn_s_setprio(1);
#pragma unroll
      for (int m = 0; m < 4; ++m)
#pragma unroll
        for (int n = 0; n < 4; ++n)
          acc[m][n] = __builtin_amdgcn_mfma_f32_16x16x32_bf16(af[m], bfr[n], acc[m][n], 0, 0, 0);
      __builtin_amdgcn_s_setprio(0);
    }
    __syncthreads();
    cur ^= 1;
  }
  if (bx < 16) {
#pragma unroll
    for (int m = 0; m < 4; ++m)
#pragma unroll
      for (int n = 0; n < 4; ++n)
#pragma unroll
        for (int r = 0; r < 4; ++r) {
          int row = m0 + wm * 64 + m * 16 + hi * 4 + r;
          int col = n0 + wn * 64 + n * 16 + lo;
          Cq[(size_t)row * 2048 + col] = f2bf(acc[m][n][r] * a1);
        }
  } else if (bx < 24) {
#pragma unroll
    for (int m = 0; m < 4; ++m)
#pragma unroll
      for (int r = 0; r < 4; ++r) {
        int row = m0 + wm * 64 + m * 16 + hi * 4 + r;
        int t = row & (TT - 1);
        float c0 = cosT[t * 32 + lo],      s0 = sinT[t * 32 + lo];
        float c1 = cosT[t * 32 + 16 + lo], s1 = sinT[t * 32 + 16 + lo];
        float x0 = acc[m][0][r], x1 = acc[m][1][r];
        float x2 = acc[m][2][r], x3 = acc[m][3][r];
        size_t base = (size_t)row * 1024 + (bx - 16) * 128 + wn * 64 + lo;
        Cr[base +  0] = f2bf((x0 * c0 - x2 * s0) * a1);
        Cr[base + 16] = f2bf((x1 * c1 - x3 * s1) * a1);
        Cr[base + 32] = f2bf((x2 * c0 + x0 * s0) * a1);
        Cr[base + 48] = f2bf((x3 * c1 + x1 * s1) * a1);
      }
  } else {
#pragma unroll
    for (int m = 0; m < 4; ++m)
#pragma unroll
      for (int n = 0; n < 4; ++n)
#pragma unroll
        for (int r = 0; r < 4; ++r) {
          int row = m0 + wm * 64 + m * 16 + hi * 4 + r;
          int col = n0 + wn * 64 + n * 16 + lo;
          Ckv[(size_t)row * 4096 + col] = f2bf(acc[m][n][r]);
        }
  }
}

// ---------- causal flash attention (round-13 proven config) ----------
__global__ __launch_bounds__(256, 2) void k_attn(const ushort* __restrict__ qb, const ushort* __restrict__ qrb,
                                                 const ushort* __restrict__ kb, const ushort* __restrict__ krb,
                                                 const ushort* __restrict__ vt, ushort* __restrict__ ao) {
  __shared__ __align__(16) ushort SH[24576];  // [Ks0|Ks1|Kr0|Kr1] = 49152 B
#define KS(buf) (SH + (buf) * 8192)
#define KR(buf) (SH + 16384 + (buf) * 4096)
  const int tid = threadIdx.x, lane = tid & 63, w = tid >> 6;
  const int cq = lane & 31;
  const int hl = lane >> 5;
  const int lin = (int)blockIdx.x + 16 * (int)blockIdx.y + 256 * (int)blockIdx.z;
  const int combo = lin & 31;
  const int pr = lin >> 5, h = combo & 15, b = combo >> 4;
  const int tA = pr, tB = 31 - pr;
  const int nch = tB + 1;
  const int myTile = (w >= 2) ? tB : tA;
  const int myDiag = myTile;
  const int qrow = myTile * 64 + (w & 1) * 32 + cq;
  const int swzK = (cq & 15) << 3;
  const int swzR = (cq & 7) << 3;

  bf16x8 qf[12];
  {
    const ushort* qp = qb + (size_t)(b * TT + qrow) * LDQ + h * HDD;
#pragma unroll
    for (int f = 0; f < 8; ++f) qf[f] = *(const bf16x8*)(qp + f * 16 + hl * 8);
    const ushort* qrp = qrb + (size_t)(b * TT + qrow) * 1024 + h * RDD;
#pragma unroll
    for (int f = 0; f < 4; ++f) qf[8 + f] = *(const bf16x8*)(qrp + f * 16 + hl * 8);
  }
  f32x16 o0, o1, o2, o3;
#pragma unroll
  for (int r = 0; r < 16; ++r) { o0[r] = 0.f; o1[r] = 0.f; o2[r] = 0.f; o3[r] = 0.f; }
  float m = -__builtin_inff(), l = 0.f;

  auto stage = [&](int buf, int kb0) {
#pragma unroll
    for (int it = 0; it < 4; ++it) {
      int cb = (tid & ~63) + it * 256;
      int c = cb + lane;
      int row = c >> 4;
      int ccg = (c & 15) ^ (row & 15);
      gld16(&KS(buf)[cb * 8], kb + (size_t)(b * TT + kb0 + row) * LDK + h * HDD + ccg * 8);
    }
#pragma unroll
    for (int it = 0; it < 2; ++it) {
      int cb = (tid & ~63) + it * 256;
      int c = cb + lane;
      int row = c >> 3;
      int ccg = (c & 7) ^ (row & 7);
      gld16(&KR(buf)[cb * 8], krb + (size_t)(b * TT + kb0 + row) * RDD + ccg * 8);
    }
  };

  stage(0, 0);
  __syncthreads();

  const ushort* vth = vt + (size_t)(b * HH + h) * HDD * TT;

  int cur = 0;
  for (int ch = 0; ch < nch; ++ch) {
    const int kb0 = ch * 64;
    if (ch + 1 < nch) stage(cur ^ 1, kb0 + 64);

    if (ch <= myDiag) {  // wave-uniform skip of dead chunks
      f32x16 s0, s1;
#pragma unroll
      for (int r = 0; r < 16; ++r) { s0[r] = 0.f; s1[r] = 0.f; }
      __builtin_amdgcn_s_setprio(1);
#pragma unroll
      for (int f = 0; f < 12; ++f) {
        const ushort* base = (f < 8) ? KS(cur) : KR(cur);
        const int stride = (f < 8) ? 128 : 64;
        const int colU = ((f < 8) ? f * 16 : (f - 8) * 16) + hl * 8;
        const int sz = (f < 8) ? swzK : swzR;
        bf16x8 k0 = *(const bf16x8*)(base + cq * stride + (colU ^ sz));
        bf16x8 k1 = *(const bf16x8*)(base + (32 + cq) * stride + (colU ^ sz));
        s0 = __builtin_amdgcn_mfma_f32_32x32x16_bf16(k0, qf[f], s0, 0, 0, 0);
        s1 = __builtin_amdgcn_mfma_f32_32x32x16_bf16(k1, qf[f], s1, 0, 0, 0);
      }
      __builtin_amdgcn_s_setprio(0);

      float mx = -__builtin_inff();
      if (ch == myDiag) {
#pragma unroll
        for (int r = 0; r < 16; ++r) {
          int kp = kb0 + (r & 3) + 8 * (r >> 2) + 4 * hl;
          if (kp > qrow) s0[r] = -__builtin_inff();
          mx = fmaxf(mx, s0[r]);
          if (kp + 32 > qrow) s1[r] = -__builtin_inff();
          mx = fmaxf(mx, s1[r]);
        }
      } else {
#pragma unroll
        for (int r = 0; r < 16; ++r) mx = fmaxf(fmaxf(mx, s0[r]), s1[r]);
      }
      mx = fmaxf(mx, xswap32(mx, hl));

      uint4v va[4], vb2[4];
      {
        const ushort* vp = vth + (size_t)(0 * 32 + cq) * TT + kb0 + hl * 8;
        va[0] = *(const uint4v*)(vp);
        va[1] = *(const uint4v*)(vp + 16);
        va[2] = *(const uint4v*)(vp + 32);
        va[3] = *(const uint4v*)(vp + 48);
      }

      bool defer = __all(mx <= m + 8.f);  // T13
      float mnew = defer ? m : fmaxf(m, mx);
      float rs = 0.f;
#pragma unroll
      for (int r = 0; r < 16; ++r) {
        s0[r] = exp2f(s0[r] - mnew); rs += s0[r];
        s1[r] = exp2f(s1[r] - mnew); rs += s1[r];
      }
      rs += xswap32(rs, hl);
      if (!defer) {
        float al = exp2f(m - mnew);
#pragma unroll
        for (int r = 0; r < 16; ++r) { o0[r] *= al; o1[r] *= al; o2[r] *= al; o3[r] *= al; }
        l = l * al + rs;
        m = mnew;
      } else {
        l += rs;
      }

      bf16x8 pf0, pf1, pf2, pf3;
#define PBUILD(PF, S, RB)                                                   \
      {                                                                     \
        unsigned a2 = pkbf(S[RB + 0], S[RB + 1]);                           \
        unsigned b2 = pkbf(S[RB + 2], S[RB + 3]);                           \
        unsigned c2 = pkbf(S[RB + 4], S[RB + 5]);                           \
        unsigned d2 = pkbf(S[RB + 6], S[RB + 7]);                           \
        u2v r02 = pl32(a2, c2);                                             \
        u2v r13 = pl32(b2, d2);                                             \
        union { uint4v u; bf16x8 v; } pb_;                                  \
        pb_.u[0] = r02[0];                                                  \
        pb_.u[1] = r13[0];                                                  \
        pb_.u[2] = r02[1];                                                  \
        pb_.u[3] = r13[1];                                                  \
        PF = pb_.v;                                                         \
      }
      PBUILD(pf0, s0, 0)
      PBUILD(pf1, s0, 8)
      PBUILD(pf2, s1, 0)
      PBUILD(pf3, s1, 8)
#undef PBUILD

#define VLOAD(DST, DT)                                                      \
      {                                                                     \
        const ushort* vp = vth + (size_t)((DT) * 32 + cq) * TT + kb0 + hl * 8;\
        DST[0] = *(const uint4v*)(vp);                                      \
        DST[1] = *(const uint4v*)(vp + 16);                                 \
        DST[2] = *(const uint4v*)(vp + 32);                                 \
        DST[3] = *(const uint4v*)(vp + 48);                                 \
      }
#define PVSTEP(OD, VS)                                                      \
      {                                                                     \
        union { uint4v u; bf16x8 v; } cv_;                                  \
        __builtin_amdgcn_s_setprio(1);                                      \
        cv_.u = VS[0]; OD = __builtin_amdgcn_mfma_f32_32x32x16_bf16(cv_.v, pf0, OD, 0, 0, 0); \
        cv_.u = VS[1]; OD = __builtin_amdgcn_mfma_f32_32x32x16_bf16(cv_.v, pf1, OD, 0, 0, 0); \
        cv_.u = VS[2]; OD = __builtin_amdgcn_mfma_f32_32x32x16_bf16(cv_.v, pf2, OD, 0, 0, 0); \
        cv_.u = VS[3]; OD = __builtin_amdgcn_mfma_f32_32x32x16_bf16(cv_.v, pf3, OD, 0, 0, 0); \
        __builtin_amdgcn_s_setprio(0);                                      \
      }
      VLOAD(vb2, 1)
      PVSTEP(o0, va)
      VLOAD(va, 2)
      PVSTEP(o1, vb2)
      VLOAD(vb2, 3)
      PVSTEP(o2, va)
      PVSTEP(o3, vb2)
#undef VLOAD
#undef PVSTEP
    }

    __syncthreads();  // drains staged gld16 for buffer cur^1
    cur ^= 1;
  }

  // ---- epilogue: per-wave LDS transpose, coalesced ao writes ----
  float inv = 1.0f / l;
  const int ebase = w * 4352;
#define OSPILL(OD, DT)                                                      \
  _Pragma("unroll")                                                         \
  for (int g = 0; g < 4; ++g) {                                             \
    ushort4v u;                                                             \
    _Pragma("unroll")                                                       \
    for (int j = 0; j < 4; ++j) u[j] = f2bf(OD[g * 4 + j] * inv);           \
    *(ushort4v*)(&SH[ebase + cq * 136 + (DT) * 32 + g * 8 + hl * 4]) = u;   \
  }
  OSPILL(o0, 0)
  OSPILL(o1, 1)
  OSPILL(o2, 2)
  OSPILL(o3, 3)
#undef OSPILL
  {
    const size_t rbase = (size_t)(b * TT + myTile * 64 + (w & 1) * 32);
#pragma unroll
    for (int p = 0; p < 8; ++p) {
      int q = p * 4 + (lane >> 4);
      uint4v v = *(const uint4v*)(&SH[ebase + q * 136 + (lane & 15) * 8]);
      *(uint4v*)(&ao[(rbase + q) * DD + h * HDD + (lane & 15) * 8]) = v;
    }
  }
#undef KS
#undef KR
}

extern "C" void kernel_launch(void* const* d_in, const int* in_sizes, int n_in,
                              void* d_out, int out_size, void* d_ws, size_t ws_size,
                              hipStream_t stream) {
  (void)in_sizes; (void)n_in; (void)out_size; (void)ws_size;
  const float* x    = (const float*)d_in[0];
  const float* Wqd  = (const float*)d_in[1];
  const float* Wqu  = (const float*)d_in[2];
  const float* Wqr  = (const float*)d_in[3];
  const float* Wkvd = (const float*)d_in[4];
  const float* Wku  = (const float*)d_in[5];
  const float* Wvu  = (const float*)d_in[6];
  const float* Wkr  = (const float*)d_in[7];
  const float* Wo   = (const float*)d_in[8];
  float* out = (float*)d_out;

  char* ws = (char*)d_ws;
  size_t off = 0;
  auto alloc = [&](size_t bytes) { void* p = ws + off; off += (bytes + 255) & ~(size_t)255; return p; };
  ushort* xb   = (ushort*)alloc((size_t)BT * DD * 2);
  ushort* w1T  = (ushort*)alloc((size_t)(LD1 + 64) * DD * 2);
  ushort* w2T  = (ushort*)alloc((size_t)3072 * LATD * 2);
  ushort* w3T  = (ushort*)alloc((size_t)4096 * LATD * 2);
  ushort* woT  = (ushort*)alloc((size_t)DD * DD * 2);
  ushort* xc   = (ushort*)alloc((size_t)BT * LD1 * 2);
  ushort* qqr  = (ushort*)alloc((size_t)BT * 2048 * 2);
  ushort* kv   = (ushort*)alloc((size_t)BT * 4096 * 2);   // [k | v], stride 4096
  ushort* qrB  = (ushort*)alloc((size_t)BT * 1024 * 2);
  ushort* krB  = (ushort*)alloc((size_t)BT * RDD * 2);
  ushort* vtB  = (ushort*)alloc((size_t)BT * DD * 2);
  ushort* aoB  = (ushort*)alloc((size_t)BT * DD * 2);
  float*  cosT = (float*)alloc((size_t)TT * 32 * 4);
  float*  sinT = (float*)alloc((size_t)TT * 32 * 4);

  float qscale = 1.4426950408889634f / sqrtf(192.0f);

  // prep: cvt (8192 blocks) + tables (256) + 8 weight transposes (9856)
  k_prep<<<dim3(18304), 256, 0, stream>>>(x, xb, cosT, sinT,
                                          Wqd, Wkvd, Wkr, Wqu, Wqr, Wku, Wvu, Wo,
                                          w1T, w2T, w3T, woT);

  // G1 (+ fused kr rope): xc = x @ [Wqd|Wkvd|Wkr], krB = rope(kr)
  k_gemm1<<<dim3(9, BT / 128), 256, 0, stream>>>(xb, w1T, xc, krB, cosT, sinT);
  // G2+G3 merged (fused qr-rope): q->qqr, rope(qr)->qrB, kv->kv
  k_gemm23<<<dim3(56, BT / 128), 256, 0, stream>>>(xc, w2T, qqr, qrB, xc + 512, w3T, kv,
                                                   qscale, cosT, sinT);

  k_vt<<<dim3(TT / 64, HDD / 64, BB * HH), 256, 0, stream>>>(kv + 2048, vtB);

  k_attn<<<dim3(16, HH, BB), 256, 0, stream>>>(qqr, qrB, kv, krB, vtB, aoB);

  // G4: out = ao @ Wo
  k_gemm<float><<<dim3(16, BT / 128), 256, 0, stream>>>(aoB, woT, out, BT, DD, DD, DD, DD, 1.0f);
}

// Round 19
// 268.512 us; speedup vs baseline: 1.0581x; 1.0080x over previous
//
#include <hip/hip_runtime.h>
#include <cmath>

typedef unsigned short ushort;
typedef __bf16 bf16x8 __attribute__((ext_vector_type(8)));
typedef float f32x4 __attribute__((ext_vector_type(4)));
typedef float f32x16 __attribute__((ext_vector_type(16)));
typedef unsigned int uint4v __attribute__((ext_vector_type(4)));
typedef unsigned int u2v __attribute__((ext_vector_type(2)));
typedef unsigned short ushort4v __attribute__((ext_vector_type(4)));

#define BB 2
#define TT 2048
#define DD 2048
#define HH 16
#define LATD 512
#define RDD 64
#define HDD 128
#define BT 4096
#define LDQ 2048
#define LDK 4096
#define LD1 1088

__device__ __forceinline__ ushort f2bf(float f) {
  union { float f; unsigned u; } v; v.f = f;
  return (ushort)((v.u + 0x7fffu + ((v.u >> 16) & 1u)) >> 16);
}
__device__ __forceinline__ float bf2f(ushort u) {
  union { unsigned u; float f; } v; v.u = ((unsigned)u) << 16; return v.f;
}
__device__ __forceinline__ f32x4 f4zero() {
  f32x4 v; v[0] = 0.f; v[1] = 0.f; v[2] = 0.f; v[3] = 0.f; return v;
}
__device__ __forceinline__ unsigned pkbf(float a, float b) {
  unsigned r;
  asm("v_cvt_pk_bf16_f32 %0, %1, %2" : "=v"(r) : "v"(a), "v"(b));
  return r;  // lo16 = bf16(a), hi16 = bf16(b)
}
__device__ __forceinline__ u2v pl32(unsigned a, unsigned b) {
  return __builtin_amdgcn_permlane32_swap(a, b, false, false);
}
__device__ __forceinline__ float xswap32(float v, int hl) {
  union { float f; unsigned u; } a; a.f = v;
  u2v r = pl32(a.u, a.u);
  union { unsigned u; float f; } o; o.u = hl ? r[0] : r[1];
  return o.f;
}

typedef __attribute__((address_space(1))) void g_void;
typedef __attribute__((address_space(3))) void l_void;
__device__ __forceinline__ void gld16(void* lds, const void* g) {
  __builtin_amdgcn_global_load_lds((g_void*)(unsigned long long)g, (l_void*)lds, 16, 0, 0);
}

// ---------- merged prep: x->bf16 cvt (bid<8192), rope tables (<8448), 8 weight transposes ----------
__global__ void k_prep(const float* __restrict__ x, ushort* __restrict__ xb,
                       float* __restrict__ cosT, float* __restrict__ sinT,
                       const float* __restrict__ Wqd, const float* __restrict__ Wkvd,
                       const float* __restrict__ Wkr, const float* __restrict__ Wqu,
                       const float* __restrict__ Wqr, const float* __restrict__ Wku,
                       const float* __restrict__ Wvu, const float* __restrict__ Wo,
                       ushort* __restrict__ w1T, ushort* __restrict__ w2T,
                       ushort* __restrict__ w3T, ushort* __restrict__ woT) {
  __shared__ float t[32][33];
  int bid = blockIdx.x, tid = threadIdx.x;
  if (bid < 8192) {  // cvt
    int i = bid * 256 + tid;
    f32x4 v = *(const f32x4*)(x + (size_t)i * 4);
    ushort4v u;
#pragma unroll
    for (int r = 0; r < 4; ++r) u[r] = f2bf(v[r]);
    *(ushort4v*)(xb + (size_t)i * 4) = u;
    return;
  }
  if (bid < 8448) {  // rope tables
    int i = (bid - 8192) * 256 + tid;
    int tt = i >> 5, jj = i & 31;
    float freq = exp2f(-(float)jj * (13.287712379549449f / 32.0f));
    float ang = (float)tt * freq;
    float s, c;
    sincosf(ang, &s, &c);
    cosT[i] = c; sinT[i] = s;
    return;
  }
  bid -= 8448;
  const float* in; ushort* out; int R, C, gx;
  if (bid < 1024)      { in = Wqd;  out = w1T;                          R = 2048; C = 512;  gx = 16; }
  else if (bid < 2048) { in = Wkvd; out = w1T + (size_t)512 * 2048;     R = 2048; C = 512;  gx = 16; bid -= 1024; }
  else if (bid < 2176) { in = Wkr;  out = w1T + (size_t)1024 * 2048;    R = 2048; C = 64;   gx = 2;  bid -= 2048; }
  else if (bid < 3200) { in = Wqu;  out = w2T;                          R = 512;  C = 2048; gx = 64; bid -= 2176; }
  else if (bid < 3712) { in = Wqr;  out = w2T + (size_t)2048 * 512;     R = 512;  C = 1024; gx = 32; bid -= 3200; }
  else if (bid < 4736) { in = Wku;  out = w3T;                          R = 512;  C = 2048; gx = 64; bid -= 3712; }
  else if (bid < 5760) { in = Wvu;  out = w3T + (size_t)2048 * 512;     R = 512;  C = 2048; gx = 64; bid -= 4736; }
  else                 { in = Wo;   out = woT;                          R = 2048; C = 2048; gx = 64; bid -= 5760; }
  int c0 = (bid % gx) * 32, r0 = (bid / gx) * 32;
  int tx = tid & 31, ty = tid >> 5;
#pragma unroll
  for (int i = 0; i < 4; ++i)
    t[ty + i * 8][tx] = in[(size_t)(r0 + ty + i * 8) * C + c0 + tx];
  __syncthreads();
#pragma unroll
  for (int i = 0; i < 4; ++i)
    out[(size_t)(c0 + ty + i * 8) * R + r0 + tx] = f2bf(t[tx][ty + i * 8]);
}

// ---------- per-head V transpose v2: 64x64 tiles, 16B global I/O, XOR-swizzled LDS ----------
__global__ void k_vt(const ushort* __restrict__ in, ushort* __restrict__ out) {
  __shared__ ushort tile[64 * 72];
  int bh = blockIdx.z, b = bh >> 4, h = bh & 15;
  int t0 = blockIdx.x * 64, d0 = blockIdx.y * 64;
  int tid = threadIdx.x;
  int lr = tid >> 3, lc = (tid & 7) * 8;
#pragma unroll
  for (int it = 0; it < 2; ++it) {
    int row = it * 32 + lr;  // t within tile
    uint4v v = *(const uint4v*)(&in[(size_t)(b * TT + t0 + row) * LDK + h * HDD + d0 + lc]);
    *(uint4v*)(&tile[row * 72 + (lc ^ ((row >> 3) << 3))]) = v;
  }
  __syncthreads();
#pragma unroll
  for (int it = 0; it < 2; ++it) {
    int dr = it * 32 + lr;   // d within tile
    union { ushort s[8]; uint4v v; } pk;
#pragma unroll
    for (int j = 0; j < 8; ++j) {
      int row = lc + j;
      pk.s[j] = tile[row * 72 + (((dr & ~7) ^ ((row >> 3) << 3)) | (dr & 7))];
    }
    *(uint4v*)(&out[((size_t)(bh * HDD + d0 + dr)) * TT + t0 + lc]) = pk.v;
  }
}

// ---------- GEMM v2: 2-phase dbuf LDS (stage next || compute cur, 1 barrier/K-step) ----------
template <typename OutT>
__global__ __launch_bounds__(256) void k_gemm(const ushort* __restrict__ A,
                                              const ushort* __restrict__ Bt,
                                              OutT* __restrict__ C,
                                              int M, int N, int K, int lda, int ldc, float alpha) {
  __shared__ __align__(16) ushort As[2][128 * 64];
  __shared__ __align__(16) ushort Bs[2][128 * 64];
  int tid = threadIdx.x;
  int lane = tid & 63, wid = tid >> 6;
  int wm = wid >> 1, wn = wid & 1;
  int lo = lane & 15, hi = lane >> 4;
  int m0 = blockIdx.y * 128, n0 = blockIdx.x * 128;
  int lr = lane >> 3, lc = (lane & 7) * 8;
  f32x4 acc[4][4];
#pragma unroll
  for (int m = 0; m < 4; ++m)
#pragma unroll
    for (int n = 0; n < 4; ++n) acc[m][n] = f4zero();

  auto stage = [&](int buf, int k0) {
#pragma unroll
    for (int it = 0; it < 4; ++it) {
      int c = wid * 4 + it;
      int row = c * 8 + lr;
      gld16(As[buf] + c * 512, A + (size_t)(m0 + row) * lda + k0 + lc);
      gld16(Bs[buf] + c * 512, Bt + (size_t)(n0 + row) * K + k0 + lc);
    }
  };

  stage(0, 0);
  __syncthreads();
  int cur = 0;
  for (int k0 = 0; k0 < K; k0 += 64) {
    if (k0 + 64 < K) stage(cur ^ 1, k0 + 64);
#pragma unroll
    for (int kk = 0; kk < 2; ++kk) {
      bf16x8 af[4], bfr[4];
#pragma unroll
      for (int m = 0; m < 4; ++m)
        af[m] = *(const bf16x8*)(As[cur] + (wm * 64 + m * 16 + lo) * 64 + kk * 32 + hi * 8);
#pragma unroll
      for (int n = 0; n < 4; ++n)
        bfr[n] = *(const bf16x8*)(Bs[cur] + (wn * 64 + n * 16 + lo) * 64 + kk * 32 + hi * 8);
      __builtin_amdgcn_s_setprio(1);
#pragma unroll
      for (int m = 0; m < 4; ++m)
#pragma unroll
        for (int n = 0; n < 4; ++n)
          acc[m][n] = __builtin_amdgcn_mfma_f32_16x16x32_bf16(af[m], bfr[n], acc[m][n], 0, 0, 0);
      __builtin_amdgcn_s_setprio(0);
    }
    __syncthreads();  // drains gld16 (next buf ready) + all reads of cur done
    cur ^= 1;
  }
#pragma unroll
  for (int m = 0; m < 4; ++m)
#pragma unroll
    for (int n = 0; n < 4; ++n)
#pragma unroll
      for (int r = 0; r < 4; ++r) {
        int row = m0 + wm * 64 + m * 16 + hi * 4 + r;
        int col = n0 + wn * 64 + n * 16 + lo;
        if (col < N) {
          float v = acc[m][n][r] * alpha;
          if constexpr (sizeof(OutT) == 4) C[(size_t)row * ldc + col] = v;
          else C[(size_t)row * ldc + col] = f2bf(v);
        }
      }
}

// ---------- G1 (2-phase) with fused kr-rope epilogue (bx==8) ----------
__global__ __launch_bounds__(256) void k_gemm1(const ushort* __restrict__ A, const ushort* __restrict__ Bt,
                                               ushort* __restrict__ C, ushort* __restrict__ Kr,
                                               const float* __restrict__ cosT, const float* __restrict__ sinT) {
  __shared__ __align__(16) ushort As[2][128 * 64];
  __shared__ __align__(16) ushort Bs[2][128 * 64];
  const int K = DD, lda = DD, ldc = LD1;
  int tid = threadIdx.x;
  int lane = tid & 63, wid = tid >> 6;
  int wm = wid >> 1, wn = wid & 1;
  int lo = lane & 15, hi = lane >> 4;
  int m0 = blockIdx.y * 128, n0 = blockIdx.x * 128;
  int bx = blockIdx.x;
  int lr = lane >> 3, lc = (lane & 7) * 8;
  f32x4 acc[4][4];
#pragma unroll
  for (int m = 0; m < 4; ++m)
#pragma unroll
    for (int n = 0; n < 4; ++n) acc[m][n] = f4zero();

  auto stage = [&](int buf, int k0) {
#pragma unroll
    for (int it = 0; it < 4; ++it) {
      int c = wid * 4 + it;
      int row = c * 8 + lr;
      gld16(As[buf] + c * 512, A + (size_t)(m0 + row) * lda + k0 + lc);
      gld16(Bs[buf] + c * 512, Bt + (size_t)(n0 + row) * K + k0 + lc);
    }
  };

  stage(0, 0);
  __syncthreads();
  int cur = 0;
  for (int k0 = 0; k0 < K; k0 += 64) {
    if (k0 + 64 < K) stage(cur ^ 1, k0 + 64);
#pragma unroll
    for (int kk = 0; kk < 2; ++kk) {
      bf16x8 af[4], bfr[4];
#pragma unroll
      for (int m = 0; m < 4; ++m)
        af[m] = *(const bf16x8*)(As[cur] + (wm * 64 + m * 16 + lo) * 64 + kk * 32 + hi * 8);
#pragma unroll
      for (int n = 0; n < 4; ++n)
        bfr[n] = *(const bf16x8*)(Bs[cur] + (wn * 64 + n * 16 + lo) * 64 + kk * 32 + hi * 8);
      __builtin_amdgcn_s_setprio(1);
#pragma unroll
      for (int m = 0; m < 4; ++m)
#pragma unroll
        for (int n = 0; n < 4; ++n)
          acc[m][n] = __builtin_amdgcn_mfma_f32_16x16x32_bf16(af[m], bfr[n], acc[m][n], 0, 0, 0);
      __builtin_amdgcn_s_setprio(0);
    }
    __syncthreads();
    cur ^= 1;
  }
  if (bx < 8) {
#pragma unroll
    for (int m = 0; m < 4; ++m)
#pragma unroll
      for (int n = 0; n < 4; ++n)
#pragma unroll
        for (int r = 0; r < 4; ++r) {
          int row = m0 + wm * 64 + m * 16 + hi * 4 + r;
          int col = n0 + wn * 64 + n * 16 + lo;
          C[(size_t)row * ldc + col] = f2bf(acc[m][n][r]);
        }
  } else if (wn == 0) {
#pragma unroll
    for (int m = 0; m < 4; ++m)
#pragma unroll
      for (int r = 0; r < 4; ++r) {
        int row = m0 + wm * 64 + m * 16 + hi * 4 + r;
        int t = row & (TT - 1);
        float c0 = cosT[t * 32 + lo],      s0 = sinT[t * 32 + lo];
        float c1 = cosT[t * 32 + 16 + lo], s1 = sinT[t * 32 + 16 + lo];
        float x0 = acc[m][0][r], x1 = acc[m][1][r];
        float x2 = acc[m][2][r], x3 = acc[m][3][r];
        size_t base = (size_t)row * 64 + lo;
        Kr[base +  0] = f2bf(x0 * c0 - x2 * s0);
        Kr[base + 16] = f2bf(x1 * c1 - x3 * s1);
        Kr[base + 32] = f2bf(x2 * c0 + x0 * s0);
        Kr[base + 48] = f2bf(x3 * c1 + x1 * s1);
      }
  }
}

// ---------- merged G2+G3 (2-phase) with fused qr-rope epilogue ----------
// bx<16: q -> stride 2048 *a1; 16..23: qr rope -> stride 1024; >=24: kv -> stride 4096.
__global__ __launch_bounds__(256) void k_gemm23(const ushort* __restrict__ A1, const ushort* __restrict__ B1,
                                                ushort* __restrict__ Cq, ushort* __restrict__ Cr,
                                                const ushort* __restrict__ A2, const ushort* __restrict__ B2,
                                                ushort* __restrict__ Ckv, float a1,
                                                const float* __restrict__ cosT, const float* __restrict__ sinT) {
  __shared__ __align__(16) ushort As[2][128 * 64];
  __shared__ __align__(16) ushort Bs[2][128 * 64];
  int bx = blockIdx.x;
  const ushort* A; const ushort* Bt; int n0;
  if (bx < 24) { A = A1; Bt = B1; n0 = bx * 128; }
  else         { A = A2; Bt = B2; n0 = (bx - 24) * 128; }
  const int K = LATD, lda = LD1;
  int tid = threadIdx.x;
  int lane = tid & 63, wid = tid >> 6;
  int wm = wid >> 1, wn = wid & 1;
  int lo = lane & 15, hi = lane >> 4;
  int m0 = blockIdx.y * 128;
  int lr = lane >> 3, lc = (lane & 7) * 8;
  f32x4 acc[4][4];
#pragma unroll
  for (int m = 0; m < 4; ++m)
#pragma unroll
    for (int n = 0; n < 4; ++n) acc[m][n] = f4zero();

  auto stage = [&](int buf, int k0) {
#pragma unroll
    for (int it = 0; it < 4; ++it) {
      int c = wid * 4 + it;
      int row = c * 8 + lr;
      gld16(As[buf] + c * 512, A + (size_t)(m0 + row) * lda + k0 + lc);
      gld16(Bs[buf] + c * 512, Bt + (size_t)(n0 + row) * K + k0 + lc);
    }
  };

  stage(0, 0);
  __syncthreads();
  int cur = 0;
  for (int k0 = 0; k0 < K; k0 += 64) {
    if (k0 + 64 < K) stage(cur ^ 1, k0 + 64);
#pragma unroll
    for (int kk = 0; kk < 2; ++kk) {
      bf16x8 af[4], bfr[4];
#pragma unroll
      for (int m = 0; m < 4; ++m)
        af[m] = *(const bf16x8*)(As[cur] + (wm * 64 + m * 16 + lo) * 64 + kk * 32 + hi * 8);
#pragma unroll
      for (int n = 0; n < 4; ++n)
        bfr[n] = *(const bf16x8*)(Bs[cur] + (wn * 64 + n * 16 + lo) * 64 + kk * 32 + hi * 8);
      __builtin_amdgcn_s_setprio(1);
#pragma unroll
      for (int m = 0; m < 4; ++m)
#pragma unroll
        for (int n = 0; n < 4; ++n)
          acc[m][n] = __builtin_amdgcn_mfma_f32_16x16x32_bf16(af[m], bfr[n], acc[m][n], 0, 0, 0);
      __builtin_amdgcn_s_setprio(0);
    }
    __syncthreads();
    cur ^= 1;
  }
  if (bx < 16) {
#pragma unroll
    for (int m = 0; m < 4; ++m)
#pragma unroll
      for (int n = 0; n < 4; ++n)
#pragma unroll
        for (int r = 0; r < 4; ++r) {
          int row = m0 + wm * 64 + m * 16 + hi * 4 + r;
          int col = n0 + wn * 64 + n * 16 + lo;
          Cq[(size_t)row * 2048 + col] = f2bf(acc[m][n][r] * a1);
        }
  } else if (bx < 24) {
#pragma unroll
    for (int m = 0; m < 4; ++m)
#pragma unroll
      for (int r = 0; r < 4; ++r) {
        int row = m0 + wm * 64 + m * 16 + hi * 4 + r;
        int t = row & (TT - 1);
        float c0 = cosT[t * 32 + lo],      s0 = sinT[t * 32 + lo];
        float c1 = cosT[t * 32 + 16 + lo], s1 = sinT[t * 32 + 16 + lo];
        float x0 = acc[m][0][r], x1 = acc[m][1][r];
        float x2 = acc[m][2][r], x3 = acc[m][3][r];
        size_t base = (size_t)row * 1024 + (bx - 16) * 128 + wn * 64 + lo;
        Cr[base +  0] = f2bf((x0 * c0 - x2 * s0) * a1);
        Cr[base + 16] = f2bf((x1 * c1 - x3 * s1) * a1);
        Cr[base + 32] = f2bf((x2 * c0 + x0 * s0) * a1);
        Cr[base + 48] = f2bf((x3 * c1 + x1 * s1) * a1);
      }
  } else {
#pragma unroll
    for (int m = 0; m < 4; ++m)
#pragma unroll
      for (int n = 0; n < 4; ++n)
#pragma unroll
        for (int r = 0; r < 4; ++r) {
          int row = m0 + wm * 64 + m * 16 + hi * 4 + r;
          int col = n0 + wn * 64 + n * 16 + lo;
          Ckv[(size_t)row * 4096 + col] = f2bf(acc[m][n][r]);
        }
  }
}

// ---------- causal flash attention v15: ring-3 staging + counted vmcnt (T3/T4) ----------
// Stage(ch+2) issued at iteration END (after V loads consumed), so compiler V-waits
// no longer drain the fresh stage; barrier = s_waitcnt vmcnt(6) + raw s_barrier
// keeps 6 loads in flight across it. Everything else = round-13 proven config.
__global__ __launch_bounds__(256, 2) void k_attn(const ushort* __restrict__ qb, const ushort* __restrict__ qrb,
                                                 const ushort* __restrict__ kb, const ushort* __restrict__ krb,
                                                 const ushort* __restrict__ vt, ushort* __restrict__ ao) {
  __shared__ __align__(16) ushort SH[36864];  // Ks[3] (3x16KB) + Kr[3] (3x8KB) = 72KB
#define KS(buf) (SH + (buf) * 8192)
#define KR(buf) (SH + 24576 + (buf) * 4096)
  const int tid = threadIdx.x, lane = tid & 63, w = tid >> 6;
  const int cq = lane & 31;
  const int hl = lane >> 5;
  const int lin = (int)blockIdx.x + 16 * (int)blockIdx.y + 256 * (int)blockIdx.z;
  const int combo = lin & 31;
  const int pr = lin >> 5, h = combo & 15, b = combo >> 4;
  const int tA = pr, tB = 31 - pr;
  const int nch = tB + 1;
  const int myTile = (w >= 2) ? tB : tA;
  const int myDiag = myTile;
  const int qrow = myTile * 64 + (w & 1) * 32 + cq;
  const int swzK = (cq & 15) << 3;
  const int swzR = (cq & 7) << 3;

  bf16x8 qf[12];
  {
    const ushort* qp = qb + (size_t)(b * TT + qrow) * LDQ + h * HDD;
#pragma unroll
    for (int f = 0; f < 8; ++f) qf[f] = *(const bf16x8*)(qp + f * 16 + hl * 8);
    const ushort* qrp = qrb + (size_t)(b * TT + qrow) * 1024 + h * RDD;
#pragma unroll
    for (int f = 0; f < 4; ++f) qf[8 + f] = *(const bf16x8*)(qrp + f * 16 + hl * 8);
  }
  f32x16 o0, o1, o2, o3;
#pragma unroll
  for (int r = 0; r < 16; ++r) { o0[r] = 0.f; o1[r] = 0.f; o2[r] = 0.f; o3[r] = 0.f; }
  float m = -__builtin_inff(), l = 0.f;

  auto stage = [&](int buf, int kb0) {
#pragma unroll
    for (int it = 0; it < 4; ++it) {
      int cb = (tid & ~63) + it * 256;
      int c = cb + lane;
      int row = c >> 4;
      int ccg = (c & 15) ^ (row & 15);
      gld16(&KS(buf)[cb * 8], kb + (size_t)(b * TT + kb0 + row) * LDK + h * HDD + ccg * 8);
    }
#pragma unroll
    for (int it = 0; it < 2; ++it) {
      int cb = (tid & ~63) + it * 256;
      int c = cb + lane;
      int row = c >> 3;
      int ccg = (c & 7) ^ (row & 7);
      gld16(&KR(buf)[cb * 8], krb + (size_t)(b * TT + kb0 + row) * RDD + ccg * 8);
    }
  };

  // prologue: stage chunks 0 and 1 (nch >= 17 always); wait for chunk 0 only
  stage(0, 0);
  stage(1, 64);
  asm volatile("s_waitcnt vmcnt(6)" ::: "memory");
  __builtin_amdgcn_s_barrier();
  __builtin_amdgcn_sched_barrier(0);

  const ushort* vth = vt + (size_t)(b * HH + h) * HDD * TT;

  int cur = 0;
  for (int ch = 0; ch < nch; ++ch) {
    const int kb0 = ch * 64;

    if (ch <= myDiag) {  // wave-uniform skip of dead chunks
      f32x16 s0, s1;
#pragma unroll
      for (int r = 0; r < 16; ++r) { s0[r] = 0.f; s1[r] = 0.f; }
      __builtin_amdgcn_s_setprio(1);
#pragma unroll
      for (int f = 0; f < 12; ++f) {
        const ushort* base = (f < 8) ? KS(cur) : KR(cur);
        const int stride = (f < 8) ? 128 : 64;
        const int colU = ((f < 8) ? f * 16 : (f - 8) * 16) + hl * 8;
        const int sz = (f < 8) ? swzK : swzR;
        bf16x8 k0 = *(const bf16x8*)(base + cq * stride + (colU ^ sz));
        bf16x8 k1 = *(const bf16x8*)(base + (32 + cq) * stride + (colU ^ sz));
        s0 = __builtin_amdgcn_mfma_f32_32x32x16_bf16(k0, qf[f], s0, 0, 0, 0);
        s1 = __builtin_amdgcn_mfma_f32_32x32x16_bf16(k1, qf[f], s1, 0, 0, 0);
      }
      __builtin_amdgcn_s_setprio(0);

      float mx = -__builtin_inff();
      if (ch == myDiag) {
#pragma unroll
        for (int r = 0; r < 16; ++r) {
          int kp = kb0 + (r & 3) + 8 * (r >> 2) + 4 * hl;
          if (kp > qrow) s0[r] = -__builtin_inff();
          mx = fmaxf(mx, s0[r]);
          if (kp + 32 > qrow) s1[r] = -__builtin_inff();
          mx = fmaxf(mx, s1[r]);
        }
      } else {
#pragma unroll
        for (int r = 0; r < 16; ++r) mx = fmaxf(fmaxf(mx, s0[r]), s1[r]);
      }
      mx = fmaxf(mx, xswap32(mx, hl));

      uint4v va[4], vb2[4];
      {
        const ushort* vp = vth + (size_t)(0 * 32 + cq) * TT + kb0 + hl * 8;
        va[0] = *(const uint4v*)(vp);
        va[1] = *(const uint4v*)(vp + 16);
        va[2] = *(const uint4v*)(vp + 32);
        va[3] = *(const uint4v*)(vp + 48);
      }

      bool defer = __all(mx <= m + 8.f);  // T13
      float mnew = defer ? m : fmaxf(m, mx);
      float rs = 0.f;
#pragma unroll
      for (int r = 0; r < 16; ++r) {
        s0[r] = exp2f(s0[r] - mnew); rs += s0[r];
        s1[r] = exp2f(s1[r] - mnew); rs += s1[r];
      }
      rs += xswap32(rs, hl);
      if (!defer) {
        float al = exp2f(m - mnew);
#pragma unroll
        for (int r = 0; r < 16; ++r) { o0[r] *= al; o1[r] *= al; o2[r] *= al; o3[r] *= al; }
        l = l * al + rs;
        m = mnew;
      } else {
        l += rs;
      }

      bf16x8 pf0, pf1, pf2, pf3;
#define PBUILD(PF, S, RB)                                                   \
      {                                                                     \
        unsigned a2 = pkbf(S[RB + 0], S[RB + 1]);                           \
        unsigned b2 = pkbf(S[RB + 2], S[RB + 3]);                           \
        unsigned c2 = pkbf(S[RB + 4], S[RB + 5]);                           \
        unsigned d2 = pkbf(S[RB + 6], S[RB + 7]);                           \
        u2v r02 = pl32(a2, c2);                                             \
        u2v r13 = pl32(b2, d2);                                             \
        union { uint4v u; bf16x8 v; } pb_;                                  \
        pb_.u[0] = r02[0];                                                  \
        pb_.u[1] = r13[0];                                                  \
        pb_.u[2] = r02[1];                                                  \
        pb_.u[3] = r13[1];                                                  \
        PF = pb_.v;                                                         \
      }
      PBUILD(pf0, s0, 0)
      PBUILD(pf1, s0, 8)
      PBUILD(pf2, s1, 0)
      PBUILD(pf3, s1, 8)
#undef PBUILD

#define VLOAD(DST, DT)                                                      \
      {                                                                     \
        const ushort* vp = vth + (size_t)((DT) * 32 + cq) * TT + kb0 + hl * 8;\
        DST[0] = *(const uint4v*)(vp);                                      \
        DST[1] = *(const uint4v*)(vp + 16);                                 \
        DST[2] = *(const uint4v*)(vp + 32);                                 \
        DST[3] = *(const uint4v*)(vp + 48);                                 \
      }
#define PVSTEP(OD, VS)                                                      \
      {                                                                     \
        union { uint4v u; bf16x8 v; } cv_;                                  \
        __builtin_amdgcn_s_setprio(1);                                      \
        cv_.u = VS[0]; OD = __builtin_amdgcn_mfma_f32_32x32x16_bf16(cv_.v, pf0, OD, 0, 0, 0); \
        cv_.u = VS[1]; OD = __builtin_amdgcn_mfma_f32_32x32x16_bf16(cv_.v, pf1, OD, 0, 0, 0); \
        cv_.u = VS[2]; OD = __builtin_amdgcn_mfma_f32_32x32x16_bf16(cv_.v, pf2, OD, 0, 0, 0); \
        cv_.u = VS[3]; OD = __builtin_amdgcn_mfma_f32_32x32x16_bf16(cv_.v, pf3, OD, 0, 0, 0); \
        __builtin_amdgcn_s_setprio(0);                                      \
      }
      VLOAD(vb2, 1)
      PVSTEP(o0, va)
      VLOAD(va, 2)
      PVSTEP(o1, vb2)
      VLOAD(vb2, 3)
      PVSTEP(o2, va)
      PVSTEP(o3, vb2)
#undef VLOAD
#undef PVSTEP
    }

    // ---- stage chunk ch+2 (2-ahead), counted-vmcnt barrier (T3/T4) ----
    if (ch + 2 < nch) {
      int nb = cur + 2; if (nb >= 3) nb -= 3;
      stage(nb, kb0 + 128);
      asm volatile("s_waitcnt vmcnt(6)" ::: "memory");  // drain stage(ch+1), keep stage(ch+2) in flight
    } else {
      asm volatile("s_waitcnt vmcnt(0)" ::: "memory");  // tail: drain everything
    }
    __builtin_amdgcn_s_barrier();
    __builtin_amdgcn_sched_barrier(0);
    cur = (cur + 1 == 3) ? 0 : cur + 1;
  }

  // ---- epilogue: per-wave LDS transpose, coalesced ao writes ----
  float inv = 1.0f / l;
  const int ebase = w * 4352;
#define OSPILL(OD, DT)                                                      \
  _Pragma("unroll")                                                         \
  for (int g = 0; g < 4; ++g) {                                             \
    ushort4v u;                                                             \
    _Pragma("unroll")                                                       \
    for (int j = 0; j < 4; ++j) u[j] = f2bf(OD[g * 4 + j] * inv);           \
    *(ushort4v*)(&SH[ebase + cq * 136 + (DT) * 32 + g * 8 + hl * 4]) = u;   \
  }
  OSPILL(o0, 0)
  OSPILL(o1, 1)
  OSPILL(o2, 2)
  OSPILL(o3, 3)
#undef OSPILL
  {
    const size_t rbase = (size_t)(b * TT + myTile * 64 + (w & 1) * 32);
#pragma unroll
    for (int p = 0; p < 8; ++p) {
      int q = p * 4 + (lane >> 4);
      uint4v v = *(const uint4v*)(&SH[ebase + q * 136 + (lane & 15) * 8]);
      *(uint4v*)(&ao[(rbase + q) * DD + h * HDD + (lane & 15) * 8]) = v;
    }
  }
#undef KS
#undef KR
}

extern "C" void kernel_launch(void* const* d_in, const int* in_sizes, int n_in,
                              void* d_out, int out_size, void* d_ws, size_t ws_size,
                              hipStream_t stream) {
  (void)in_sizes; (void)n_in; (void)out_size; (void)ws_size;
  const float* x    = (const float*)d_in[0];
  const float* Wqd  = (const float*)d_in[1];
  const float* Wqu  = (const float*)d_in[2];
  const float* Wqr  = (const float*)d_in[3];
  const float* Wkvd = (const float*)d_in[4];
  const float* Wku  = (const float*)d_in[5];
  const float* Wvu  = (const float*)d_in[6];
  const float* Wkr  = (const float*)d_in[7];
  const float* Wo   = (const float*)d_in[8];
  float* out = (float*)d_out;

  char* ws = (char*)d_ws;
  size_t off = 0;
  auto alloc = [&](size_t bytes) { void* p = ws + off; off += (bytes + 255) & ~(size_t)255; return p; };
  ushort* xb   = (ushort*)alloc((size_t)BT * DD * 2);
  ushort* w1T  = (ushort*)alloc((size_t)(LD1 + 64) * DD * 2);
  ushort* w2T  = (ushort*)alloc((size_t)3072 * LATD * 2);
  ushort* w3T  = (ushort*)alloc((size_t)4096 * LATD * 2);
  ushort* woT  = (ushort*)alloc((size_t)DD * DD * 2);
  ushort* xc   = (ushort*)alloc((size_t)BT * LD1 * 2);
  ushort* qqr  = (ushort*)alloc((size_t)BT * 2048 * 2);
  ushort* kv   = (ushort*)alloc((size_t)BT * 4096 * 2);   // [k | v], stride 4096
  ushort* qrB  = (ushort*)alloc((size_t)BT * 1024 * 2);
  ushort* krB  = (ushort*)alloc((size_t)BT * RDD * 2);
  ushort* vtB  = (ushort*)alloc((size_t)BT * DD * 2);
  ushort* aoB  = (ushort*)alloc((size_t)BT * DD * 2);
  float*  cosT = (float*)alloc((size_t)TT * 32 * 4);
  float*  sinT = (float*)alloc((size_t)TT * 32 * 4);

  float qscale = 1.4426950408889634f / sqrtf(192.0f);

  // prep: cvt (8192 blocks) + tables (256) + 8 weight transposes (9856)
  k_prep<<<dim3(18304), 256, 0, stream>>>(x, xb, cosT, sinT,
                                          Wqd, Wkvd, Wkr, Wqu, Wqr, Wku, Wvu, Wo,
                                          w1T, w2T, w3T, woT);

  // G1 (+ fused kr rope): xc = x @ [Wqd|Wkvd|Wkr], krB = rope(kr)
  k_gemm1<<<dim3(9, BT / 128), 256, 0, stream>>>(xb, w1T, xc, krB, cosT, sinT);
  // G2+G3 merged (fused qr-rope): q->qqr, rope(qr)->qrB, kv->kv
  k_gemm23<<<dim3(56, BT / 128), 256, 0, stream>>>(xc, w2T, qqr, qrB, xc + 512, w3T, kv,
                                                   qscale, cosT, sinT);

  k_vt<<<dim3(TT / 64, HDD / 64, BB * HH), 256, 0, stream>>>(kv + 2048, vtB);

  k_attn<<<dim3(16, HH, BB), 256, 0, stream>>>(qqr, qrB, kv, krB, vtB, aoB);

  // G4: out = ao @ Wo
  k_gemm<float><<<dim3(16, BT / 128), 256, 0, stream>>>(aoB, woT, out, BT, DD, DD, DD, DD, 1.0f);
}